// Round 1
// baseline (416.341 us; speedup 1.0000x reference)
//
#include <hip/hip_runtime.h>
#include <math.h>

// GodContinuousAreaModel: B=32, D_IN=1024, A=4, N_PER=2048, N=8192, OUT=11.
// area_idx = arange(N) (identity) -> direct indexing. Dominant cost: stream
// synapses_w (256 MB f32) once. Roofline ~290 MB / 6.3 TB/s ~= 46 us.
// R1: dynamic acc index -> scratch spill (WRITE 2.4 GB). Fixed R2.
// R2: VALU-FMA design: ~167 us (VALU floor + LDS re-read + barrier drain).
// R3: MFMA with direct-to-reg A-frags: ~154 us. Scattered 64 B loads ran the
//     HBM stream at 1.9 TB/s (outstanding-miss tags exhausted).
// R4: m97-style: W staged to LDS via global_load_lds (1 KB contiguous per
//     instr, dbuf, pad-to-260 rows), A-frags from LDS (f32->bf16 in-reg,
//     coeff folded), B-frags direct from L2-hot zg. Total 410.6.
// R5: timed region decomposes as ~2x161 us harness 1-GiB workspace fills +
//     ~89 us of our kernels (k_main ~50 us ~= HBM floor). Remaining lever:
//     k_proj only re-reads the Znew tile k_main already has in LDS. Fold the
//     output projection into k_main's epilogue (atomicAdd partials into raw,
//     512 staggered updates/address -> no contention), drop k_proj + Zn.
#define BATCH 32
#define DIN   1024
#define NPER  2048
#define NTOT  8192
#define KTOT  9216          // 8192 synapse + 1024 receptor columns
#define KC    256           // k-chunk
#define NCH   36            // KTOT / KC  (32 synapse + 4 receptor chunks)
#define AROW  260           // padded LDS row: m*260%32 = 4m -> uniform banks

typedef __attribute__((ext_vector_type(8))) short short8;   // 8 bf16
typedef __attribute__((ext_vector_type(4))) float f32x4;

typedef __attribute__((address_space(1))) const unsigned int gu32_t;
typedef __attribute__((address_space(3))) unsigned int su32_t;

__device__ __forceinline__ void load_lds16(const float* g, float* l) {
  __builtin_amdgcn_global_load_lds((gu32_t*)g, (su32_t*)l, 16, 0, 0);
}

__device__ __forceinline__ unsigned short f2bf(float f) {   // RNE f32->bf16
  unsigned u = __float_as_uint(f);
  u += 0x7FFF + ((u >> 16) & 1);
  return (unsigned short)(u >> 16);
}

// ---- kernel 1: gsum[a] = sum_{b,n} |Z0[b,a,n]| ----------------------------
__global__ void k_gate(const float* __restrict__ Z0, float* __restrict__ gsum) {
  const int a = blockIdx.x >> 3;
  const int slice = blockIdx.x & 7;
  const int tid = threadIdx.x;
  float s = 0.f;
#pragma unroll
  for (int it = 0; it < 8; ++it) {
    const int idx = it * 256 + tid;
    const int b = slice * 4 + (idx >> 9);
    const int n4 = idx & 511;
    const float4 z = *(const float4*)(Z0 + (size_t)b * NTOT + a * NPER + n4 * 4);
    s += fabsf(z.x) + fabsf(z.y) + fabsf(z.z) + fabsf(z.w);
  }
#pragma unroll
  for (int off = 32; off > 0; off >>= 1) s += __shfl_down(s, off);
  __shared__ float wsum[4];
  if ((tid & 63) == 0) wsum[tid >> 6] = s;
  __syncthreads();
  if (tid == 0) atomicAdd(&gsum[a], wsum[0] + wsum[1] + wsum[2] + wsum[3]);
}

// ---- kernel 2: Zg[b][k] = bf16( gate-scaled Z0 | x ), K=9216 --------------
__global__ void k_prep(const float* __restrict__ Z0, const float* __restrict__ x,
                       const float* __restrict__ gsum, unsigned short* __restrict__ zg) {
  const int idx = blockIdx.x * 256 + threadIdx.x;
  const int b = idx / (KTOT / 4);
  const int k = (idx % (KTOT / 4)) * 4;
  float4 v; float g;
  if (k < NTOT) {
    v = *(const float4*)(Z0 + (size_t)b * NTOT + k);
    g = (gsum[k >> 11] * (1.f / (BATCH * NPER)) > 0.05f) ? 1.f : 0.f;
  } else {
    v = *(const float4*)(x + (size_t)b * DIN + (k - NTOT));
    g = 1.f;
  }
  ushort4 o;
  o.x = f2bf(v.x * g); o.y = f2bf(v.y * g);
  o.z = f2bf(v.z * g); o.w = f2bf(v.w * g);
  *(ushort4*)(zg + (size_t)b * KTOT + k) = o;
}

// ---- kernel 3: MFMA GEMM, m97-style staged A-stream + fused projection -----
// 512 blocks x 256 thr (4 waves). Block owns 16 rows, all 32 batches, full K.
// Per 256-k chunk: 16 global_load_lds (1 KB contiguous each, one per row,
// dbuf) stage W f32 -> LDS; wave w computes k-subchunks 2w, 2w+1 (A-frags
// via ds_read_b128 from padded LDS rows, f32->bf16 with coeff folded);
// B-frags (bf16) direct from zg (L2-resident, 576 KB). Epilogue reduces the
// 4 waves' K-partials, applies bias+tanh into a 16x32 LDS tile, then folds
// the output-lobe projection: raw[j,b] += sum_r olw[j,r]*Znew[r,b] via one
// atomicAdd per (j,b) per block (updates staggered across ~50 us -> no
// contention). MFMA maps (learn_hip-verified): A[m=lane&15][k=q*8+j],
// B[n=lane&15][k=q*8+j], D[row=q*4+reg][col=lane&15].
__launch_bounds__(256, 4)
__global__ void k_main(const float* __restrict__ Rw, const float* __restrict__ rbias,
                       const float* __restrict__ Sw, const float* __restrict__ sbias,
                       const float* __restrict__ gsum, const unsigned short* __restrict__ zg,
                       const float* __restrict__ olw, float* __restrict__ raw) {
  __shared__ __align__(16) float As[2][16][AROW];   // 33.3 KB dbuf W tile
  __shared__ float red[8][16][17];                  // 8.7 KB epilogue partials
  __shared__ float Zs[16][33];                      // 2.1 KB tanh'd Znew tile
  const int tid = threadIdx.x;
  const int w = tid >> 6, lane = tid & 63;
  const int m = lane & 15, quad = lane >> 4;
  const int r0 = blockIdx.x * 16;
  const int o = r0 >> 11;              // output area of this block

  float g[4], coeff[4];
#pragma unroll
  for (int a = 0; a < 4; ++a) {
    g[a] = (gsum[a] * (1.f / (BATCH * NPER)) > 0.05f) ? 1.f : 0.f;
    coeff[a] = g[a] * ((a == o) ? 0.8f : 0.1f);
  }

  // wave w stages rows 4w..4w+3 of the next chunk (1 KB contiguous each)
  auto stage = [&](int c, int buf) {
    const int k0 = c * KC;
    const float* base; int rs;
    if (k0 < NTOT) { base = Sw + (size_t)r0 * NTOT + k0;          rs = NTOT; }
    else           { base = Rw + (size_t)r0 * DIN + (k0 - NTOT);  rs = DIN;  }
#pragma unroll
    for (int i = 0; i < 4; ++i) {
      const int r = w * 4 + i;
      load_lds16(base + (size_t)r * rs + lane * 4, &As[buf][r][0]);
    }
  };

  f32x4 acc0 = {0.f, 0.f, 0.f, 0.f};   // n = 0..15
  f32x4 acc1 = {0.f, 0.f, 0.f, 0.f};   // n = 16..31

  const unsigned short* zg0 = zg + (size_t)m * KTOT;
  const unsigned short* zg1 = zg + (size_t)(m + 16) * KTOT;

  stage(0, 0);
  for (int c = 0; c < NCH; ++c) {
    const int buf = c & 1;
    __syncthreads();                   // chunk c staged; other buf free
    if (c + 1 < NCH) stage(c + 1, buf ^ 1);   // async, overlaps compute
    const float s = (c < 32) ? coeff[c >> 3] : 1.f;
#pragma unroll
    for (int u = 0; u < 2; ++u) {
      const int ks = (w * 2 + u) * 32;            // k-offset within chunk
      const float* ap = &As[buf][m][ks + quad * 8];
      const float4 a0 = *(const float4*)ap;       // ds_read_b128, uniform banks
      const float4 a1 = *(const float4*)(ap + 4);
      short8 af;
      af[0] = (short)f2bf(a0.x * s); af[1] = (short)f2bf(a0.y * s);
      af[2] = (short)f2bf(a0.z * s); af[3] = (short)f2bf(a0.w * s);
      af[4] = (short)f2bf(a1.x * s); af[5] = (short)f2bf(a1.y * s);
      af[6] = (short)f2bf(a1.z * s); af[7] = (short)f2bf(a1.w * s);
      const int kg = c * KC + ks + quad * 8;      // global k for B
      const short8 b0 = *(const short8*)(zg0 + kg);   // L2-hot
      const short8 b1 = *(const short8*)(zg1 + kg);
      acc0 = __builtin_amdgcn_mfma_f32_16x16x32_bf16(af, b0, acc0, 0, 0, 0);
      acc1 = __builtin_amdgcn_mfma_f32_16x16x32_bf16(af, b1, acc1, 0, 0, 0);
    }
  }

  // ---- epilogue: sum 4 waves' K-partials, bias + tanh into LDS tile --------
#pragma unroll
  for (int r = 0; r < 4; ++r) {
    red[w * 2 + 0][quad * 4 + r][m] = acc0[r];
    red[w * 2 + 1][quad * 4 + r][m] = acc1[r];
  }
  __syncthreads();
  const float gate_o = g[o];
#pragma unroll
  for (int t = tid; t < 512; t += 256) {
    const int row = t >> 5, n = t & 31;
    const int h = n >> 4, nn = n & 15;
    float v = red[0 + h][row][nn] + red[2 + h][row][nn] +
              red[4 + h][row][nn] + red[6 + h][row][nn];
    const int r = r0 + row;
    v += rbias[r] + gate_o * sbias[r];
    Zs[row][n] = tanhf(v);
  }
  __syncthreads();

  // ---- fused output projection: raw[j,b] += sum_row olw[j,r0+row]*Zs[row][b]
  // 352 (j,b) pairs; olw load is wave-uniform per j (L1 broadcast); Zs reads
  // are conflict-free (stride-33 rows) and broadcast across the two 32-lane
  // halves. One device-scope atomicAdd per pair per block.
  for (int t = tid; t < 352; t += 256) {
    const int j = t >> 5, b = t & 31;
    float sacc = 0.f;
#pragma unroll
    for (int row = 0; row < 16; ++row)
      sacc = fmaf(olw[(size_t)j * NTOT + r0 + row], Zs[row][b], sacc);
    atomicAdd(&raw[t], sacc);
  }
}

// ---- kernel 4: bias + split logits / sigmoid gate into d_out ---------------
__global__ void k_fin(const float* __restrict__ raw, const float* __restrict__ olb,
                      float* __restrict__ out) {
  const int t = threadIdx.x;
  if (t < 352) {
    const int j = t >> 5, b = t & 31;
    const float v = raw[j * BATCH + b] + olb[j];
    if (j < 10) out[b * 10 + j] = v;
    else        out[320 + b] = 1.f / (1.f + expf(-v));
  }
}

extern "C" void kernel_launch(void* const* d_in, const int* in_sizes, int n_in,
                              void* d_out, int out_size, void* d_ws, size_t ws_size,
                              hipStream_t stream) {
  const float* x    = (const float*)d_in[0];
  const float* Z0   = (const float*)d_in[1];
  const float* Rw   = (const float*)d_in[2];
  const float* rb_  = (const float*)d_in[3];
  const float* Sw   = (const float*)d_in[4];
  const float* sb_  = (const float*)d_in[5];
  const float* olw  = (const float*)d_in[6];
  const float* olb  = (const float*)d_in[7];
  // d_in[8] (area_idx) is arange(N): identity permutation, not needed.

  float* ws   = (float*)d_ws;
  float* gsum = ws;                 // [4]    gate |Z0| sums
  float* raw  = ws + 8;             // [352]  output-lobe accumulators
  unsigned short* zg = (unsigned short*)(ws + 512);  // [32][9216] bf16

  hipMemsetAsync(d_ws, 0, 512 * sizeof(float), stream);  // zero gsum + raw
  k_gate<<<32, 256, 0, stream>>>(Z0, gsum);
  k_prep<<<BATCH * KTOT / 1024, 256, 0, stream>>>(Z0, x, gsum, zg);
  k_main<<<NTOT / 16, 256, 0, stream>>>(Rw, rb_, Sw, sb_, gsum, zg, olw, raw);
  k_fin<<<1, 384, 0, stream>>>(raw, olb, (float*)d_out);
}

// Round 6
// 411.001 us; speedup vs baseline: 1.0130x; 1.0130x over previous
//
#include <hip/hip_runtime.h>
#include <math.h>

// GodContinuousAreaModel: B=32, D_IN=1024, A=4, N_PER=2048, N=8192, OUT=11.
// area_idx = arange(N) (identity) -> direct indexing. Dominant cost: stream
// synapses_w (256 MB f32) once. Roofline ~290 MB / 6.3 TB/s ~= 46 us.
// R2: VALU-FMA design: ~167 us. R3: direct-to-reg MFMA: ~154 us (scattered
//     64 B loads -> 1.9 TB/s). R4: m97-style global_load_lds staging: 410.6
//     total (timed region = ~2x161 us harness 1-GiB fills + ~89 us ours).
// R5: fused k_proj into k_main epilogue (atomicAdd partials): 416.3 -- within
//     fill jitter; kept (strictly less work).
// R6-R8: counted-vmcnt pipeline (inline-asm vmcnt(8)+s_barrier) -> THREE
//     consecutive "container failed twice" infra errors; never ran.
// R9: disambiguation -- reverted k_main to the R5-VERIFIED sync structure
//     (single __syncthreads per chunk, no asm barriers) + one safe fix:
//     chunk-c zg loads hoisted BEFORE stage(c+1) (R5's order made the
//     compiler's in-order vmcnt wait for zg drain the stage prefetch ->
//     zero overlap). ALSO failed with the same acquire-level error.
// R10: 4th consecutive failure, now on a near-verified structure -> infra
//     ~95% confirmed sick (prior successful round already showed 2078 s for
//     a 280 MB push). k_pre re-audited (block-uniform barrier, all bounds
//     exact). Resubmitting R9 unchanged to wait out infra and preserve the
//     A/B vs R5's 416.3.
#define BATCH 32
#define DIN   1024
#define NPER  2048
#define NTOT  8192
#define KTOT  9216          // 8192 synapse + 1024 receptor columns
#define KC    256           // k-chunk
#define NCH   36            // KTOT / KC  (32 synapse + 4 receptor chunks)
#define AROW  260           // padded LDS row: m*260%32 = 4m -> uniform banks

typedef __attribute__((ext_vector_type(8))) short short8;   // 8 bf16
typedef __attribute__((ext_vector_type(4))) float f32x4;

typedef __attribute__((address_space(1))) const unsigned int gu32_t;
typedef __attribute__((address_space(3))) unsigned int su32_t;

__device__ __forceinline__ void load_lds16(const float* g, float* l) {
  __builtin_amdgcn_global_load_lds((gu32_t*)g, (su32_t*)l, 16, 0, 0);
}

__device__ __forceinline__ unsigned short f2bf(float f) {   // RNE f32->bf16
  unsigned u = __float_as_uint(f);
  u += 0x7FFF + ((u >> 16) & 1);
  return (unsigned short)(u >> 16);
}

// ---- kernel 1: fused prep (blocks 0..287) + gate reduce (blocks 288..319) --
// prep: zg[b][k] = bf16( Z0 | x ), UNgated (gate lives in k_main's coeff;
// g in {0,1} so g^2 == g -> bit-identical). gate: gsum[a] = sum|Z0[:,a,:]|.
__global__ void k_pre(const float* __restrict__ Z0, const float* __restrict__ x,
                      unsigned short* __restrict__ zg, float* __restrict__ gsum) {
  __shared__ float wsum[4];
  const int bid = blockIdx.x;
  const int tid = threadIdx.x;
  if (bid < 288) {                       // ---- prep path ----
    const int idx = bid * 256 + tid;
    const int b = idx / (KTOT / 4);
    const int k = (idx % (KTOT / 4)) * 4;
    float4 v;
    if (k < NTOT) v = *(const float4*)(Z0 + (size_t)b * NTOT + k);
    else          v = *(const float4*)(x  + (size_t)b * DIN + (k - NTOT));
    ushort4 o;
    o.x = f2bf(v.x); o.y = f2bf(v.y); o.z = f2bf(v.z); o.w = f2bf(v.w);
    *(ushort4*)(zg + (size_t)b * KTOT + k) = o;
  } else {                               // ---- gate path ----
    const int gb = bid - 288;
    const int a = gb >> 3;
    const int slice = gb & 7;
    float s = 0.f;
#pragma unroll
    for (int it = 0; it < 8; ++it) {
      const int idx = it * 256 + tid;
      const int b = slice * 4 + (idx >> 9);
      const int n4 = idx & 511;
      const float4 z = *(const float4*)(Z0 + (size_t)b * NTOT + a * NPER + n4 * 4);
      s += fabsf(z.x) + fabsf(z.y) + fabsf(z.z) + fabsf(z.w);
    }
#pragma unroll
    for (int off = 32; off > 0; off >>= 1) s += __shfl_down(s, off);
    if ((tid & 63) == 0) wsum[tid >> 6] = s;
    __syncthreads();
    if (tid == 0) atomicAdd(&gsum[a], wsum[0] + wsum[1] + wsum[2] + wsum[3]);
  }
}

// ---- kernel 2: MFMA GEMM, R5-verified sync structure + zg-hoist ------------
// 512 blocks x 256 thr (4 waves). Block owns 16 rows, all 32 batches, full K.
// Per 256-k chunk: __syncthreads (chunk staged), zg B-frags for THIS chunk
// loaded to regs FIRST (so the compiler's in-order vmcnt wait for them does
// not drain the next stage), then 16 global_load_lds stage chunk c+1 (1 KB
// contiguous each, dbuf), then A-frags via ds_read_b128 from padded LDS rows
// (f32->bf16 with coeff folded) and 4 MFMA per wave. Epilogue: reduce 4
// waves' K-partials, bias+tanh into LDS tile, fused output-lobe projection
// via one atomicAdd per (j,b). MFMA maps (learn_hip-verified):
// A[m=lane&15][k=q*8+j], B[n=lane&15][k], D[row=q*4+reg][col=lane&15].
__launch_bounds__(256, 4)
__global__ void k_main(const float* __restrict__ Rw, const float* __restrict__ rbias,
                       const float* __restrict__ Sw, const float* __restrict__ sbias,
                       const float* __restrict__ gsum, const unsigned short* __restrict__ zg,
                       const float* __restrict__ olw, float* __restrict__ raw) {
  __shared__ __align__(16) float As[2][16][AROW];   // 33.3 KB dbuf W tile
  __shared__ float red[8][16][17];                  // 8.7 KB epilogue partials
  __shared__ float Zs[16][33];                      // 2.1 KB tanh'd Znew tile
  const int tid = threadIdx.x;
  const int w = tid >> 6, lane = tid & 63;
  const int m = lane & 15, quad = lane >> 4;
  const int r0 = blockIdx.x * 16;
  const int o = r0 >> 11;              // output area of this block

  float g[4], coeff[4];
#pragma unroll
  for (int a = 0; a < 4; ++a) {
    g[a] = (gsum[a] * (1.f / (BATCH * NPER)) > 0.05f) ? 1.f : 0.f;
    coeff[a] = g[a] * ((a == o) ? 0.8f : 0.1f);
  }

  // wave w stages rows 4w..4w+3 of chunk c (4x 1 KB contiguous global_load_lds)
  auto stage = [&](int c, int buf) {
    const int k0 = c * KC;
    const float* base; int rs;
    if (k0 < NTOT) { base = Sw + (size_t)r0 * NTOT + k0;          rs = NTOT; }
    else           { base = Rw + (size_t)r0 * DIN + (k0 - NTOT);  rs = DIN;  }
#pragma unroll
    for (int i = 0; i < 4; ++i) {
      const int r = w * 4 + i;
      load_lds16(base + (size_t)r * rs + lane * 4, &As[buf][r][0]);
    }
  };

  f32x4 acc0 = {0.f, 0.f, 0.f, 0.f};   // n = 0..15
  f32x4 acc1 = {0.f, 0.f, 0.f, 0.f};   // n = 16..31

  const unsigned short* zg0 = zg + (size_t)m * KTOT;
  const unsigned short* zg1 = zg + (size_t)(m + 16) * KTOT;
  const int kb0 = (w * 2) * 32 + quad * 8;   // this wave's k-base within chunk

  stage(0, 0);
  for (int c = 0; c < NCH; ++c) {
    const int buf = c & 1;
    __syncthreads();                   // chunk c staged; other buf free
    // zg B-frags for chunk c FIRST (before next stage), so the in-order
    // vmcnt wait on them leaves the c+1 stage loads in flight.
    const int kg = c * KC + kb0;
    const short8 z0 = *(const short8*)(zg0 + kg);        // L2-hot
    const short8 z1 = *(const short8*)(zg1 + kg);
    const short8 z2 = *(const short8*)(zg0 + kg + 32);
    const short8 z3 = *(const short8*)(zg1 + kg + 32);
    asm volatile("" ::: "memory");     // pin: zg issued before stage(c+1)
    if (c + 1 < NCH) stage(c + 1, buf ^ 1);   // async, overlaps compute
    const float s = (c < 32) ? coeff[c >> 3] : 1.f;
#pragma unroll
    for (int u = 0; u < 2; ++u) {
      const float* ap = &As[buf][m][(w * 2 + u) * 32 + quad * 8];
      const float4 a0 = *(const float4*)ap;       // ds_read_b128, uniform banks
      const float4 a1 = *(const float4*)(ap + 4);
      short8 af;
      af[0] = (short)f2bf(a0.x * s); af[1] = (short)f2bf(a0.y * s);
      af[2] = (short)f2bf(a0.z * s); af[3] = (short)f2bf(a0.w * s);
      af[4] = (short)f2bf(a1.x * s); af[5] = (short)f2bf(a1.y * s);
      af[6] = (short)f2bf(a1.z * s); af[7] = (short)f2bf(a1.w * s);
      acc0 = __builtin_amdgcn_mfma_f32_16x16x32_bf16(af, (u ? z2 : z0), acc0, 0, 0, 0);
      acc1 = __builtin_amdgcn_mfma_f32_16x16x32_bf16(af, (u ? z3 : z1), acc1, 0, 0, 0);
    }
  }

  // ---- epilogue: sum 4 waves' K-partials, bias + tanh into LDS tile --------
#pragma unroll
  for (int r = 0; r < 4; ++r) {
    red[w * 2 + 0][quad * 4 + r][m] = acc0[r];
    red[w * 2 + 1][quad * 4 + r][m] = acc1[r];
  }
  __syncthreads();
  const float gate_o = g[o];
#pragma unroll
  for (int t = tid; t < 512; t += 256) {
    const int row = t >> 5, n = t & 31;
    const int h = n >> 4, nn = n & 15;
    float v = red[0 + h][row][nn] + red[2 + h][row][nn] +
              red[4 + h][row][nn] + red[6 + h][row][nn];
    const int r = r0 + row;
    v += rbias[r] + gate_o * sbias[r];
    Zs[row][n] = tanhf(v);
  }
  __syncthreads();

  // ---- fused output projection: raw[j,b] += sum_row olw[j,r0+row]*Zs[row][b]
  for (int t = tid; t < 352; t += 256) {
    const int j = t >> 5, b = t & 31;
    float sacc = 0.f;
#pragma unroll
    for (int row = 0; row < 16; ++row)
      sacc = fmaf(olw[(size_t)j * NTOT + r0 + row], Zs[row][b], sacc);
    atomicAdd(&raw[t], sacc);
  }
}

// ---- kernel 3: bias + split logits / sigmoid gate into d_out ---------------
__global__ void k_fin(const float* __restrict__ raw, const float* __restrict__ olb,
                      float* __restrict__ out) {
  const int t = threadIdx.x;
  if (t < 352) {
    const int j = t >> 5, b = t & 31;
    const float v = raw[j * BATCH + b] + olb[j];
    if (j < 10) out[b * 10 + j] = v;
    else        out[320 + b] = 1.f / (1.f + expf(-v));
  }
}

extern "C" void kernel_launch(void* const* d_in, const int* in_sizes, int n_in,
                              void* d_out, int out_size, void* d_ws, size_t ws_size,
                              hipStream_t stream) {
  const float* x    = (const float*)d_in[0];
  const float* Z0   = (const float*)d_in[1];
  const float* Rw   = (const float*)d_in[2];
  const float* rb_  = (const float*)d_in[3];
  const float* Sw   = (const float*)d_in[4];
  const float* sb_  = (const float*)d_in[5];
  const float* olw  = (const float*)d_in[6];
  const float* olb  = (const float*)d_in[7];
  // d_in[8] (area_idx) is arange(N): identity permutation, not needed.

  float* ws   = (float*)d_ws;
  float* gsum = ws;                 // [4]    gate |Z0| sums
  float* raw  = ws + 8;             // [352]  output-lobe accumulators
  unsigned short* zg = (unsigned short*)(ws + 512);  // [32][9216] bf16

  hipMemsetAsync(d_ws, 0, 512 * sizeof(float), stream);  // zero gsum + raw
  k_pre<<<320, 256, 0, stream>>>(Z0, x, zg, gsum);
  k_main<<<NTOT / 16, 256, 0, stream>>>(Rw, rb_, Sw, sb_, gsum, zg, olw, raw);
  k_fin<<<1, 384, 0, stream>>>(raw, olb, (float*)d_out);
}